// Round 15
// baseline (126.323 us; speedup 1.0000x reference)
//
#include <hip/hip_runtime.h>

typedef unsigned short u16;
typedef __attribute__((ext_vector_type(8))) short bf16x8;
typedef __attribute__((ext_vector_type(4))) short bf16x4;
typedef __attribute__((ext_vector_type(4))) float f32x4;

#define TP 28
#define NB 4096
#define L2E 1.4426950408889634f

__device__ __forceinline__ u16 f2bf(float x) {
  union { float f; unsigned u; } v; v.f = x;
  unsigned u = v.u;
  return (u16)((u + 0x7fffu + ((u >> 16) & 1u)) >> 16);
}
__device__ __forceinline__ float bf2f(u16 h) {
  union { unsigned u; float f; } v; v.u = ((unsigned)h) << 16; return v.f;
}
__device__ __forceinline__ float rcp_(float x) {
  float r;
  asm("v_rcp_f32 %0, %1" : "=v"(r) : "v"(x));
  return r;
}
__device__ __forceinline__ float exp2_(float x) {
  float r;
  asm("v_exp_f32 %0, %1" : "=v"(r) : "v"(x));
  return r;
}
// log2-domain gates (weights pre-scaled by L2E / 2*L2E)
__device__ __forceinline__ float sigm2(float x) { return rcp_(1.0f + exp2_(-x)); }
__device__ __forceinline__ float tanh2(float x) { return 1.0f - 2.0f * rcp_(1.0f + exp2_(x)); }
__device__ __forceinline__ float sigm(float x) { return rcp_(1.0f + __expf(-x)); }
__device__ __forceinline__ float leaky(float x) { return x >= 0.0f ? x : 0.1f * x; }
__device__ __forceinline__ f32x4 mfma16(bf16x8 a, bf16x8 b, f32x4 c) {
  return __builtin_amdgcn_mfma_f32_16x16x32_bf16(a, b, c, 0, 0, 0);
}
__device__ __forceinline__ bf16x8 pack8s(float4 a, float4 b, float s) {
  bf16x8 f;
  f[0] = (short)f2bf(a.x * s); f[1] = (short)f2bf(a.y * s);
  f[2] = (short)f2bf(a.z * s); f[3] = (short)f2bf(a.w * s);
  f[4] = (short)f2bf(b.x * s); f[5] = (short)f2bf(b.y * s);
  f[6] = (short)f2bf(b.z * s); f[7] = (short)f2bf(b.w * s);
  return f;
}
__device__ __forceinline__ bf16x8 ldfrag8s(const float* p, float s) {
  float4 u0 = *(const float4*)p;
  float4 u1 = *(const float4*)(p + 4);
  return pack8s(u0, u1, s);
}

// ---------------- conv1: async global_load_lds staging (f32 in LDS) ----------------
// 256 thr / 4 waves / 2 batches. 48 x 1KB DMA chunks -> flat f32 LDS; wt filled
// concurrently; one barrier (drains vmcnt); f32->bf16 conversion in MFMA loop.
// LDS ~66.6 KB -> 2 blocks/CU; block B DMAs while block A computes.
__global__ __launch_bounds__(256, 2) void k_conv1(
    const float* __restrict__ poses, const float* __restrict__ w1,
    const float* __restrict__ b1, float* __restrict__ y1,
    float* __restrict__ p1)
{
  __shared__ __align__(16) float xsf[12288];   // 2 x 6120 f32 + pad (DMA target)
  __shared__ __align__(16) u16 wt[16][544];    // [co][k], k = tap*180+ci; k>=540 zero
  __shared__ float sp[4][16];
  __shared__ float sq[4][16];
  const int tid = threadIdx.x;
  const int lane = tid & 63;
  const int wv = tid >> 6;     // 0..3
  const int b0 = blockIdx.x * 2;

  // 48 async 1KB chunks; wave w issues chunks w*12 .. w*12+11.
  // Source index clamped so the final block never reads OOB (duplicated finite
  // values land only in the zero-weight k>=540 pad region).
  {
    const long limit = (long)NB * 1530 - 1;   // last valid float4 index
#pragma unroll
    for (int j = 0; j < 12; ++j) {
      const int c = wv * 12 + j;
      long fidx = (long)b0 * 1530 + (long)(c * 64 + lane);
      if (fidx > limit) fidx = limit;
      __builtin_amdgcn_global_load_lds(
          (const __attribute__((address_space(1))) void*)(poses + fidx * 4),
          (__attribute__((address_space(3))) void*)(xsf + c * 256),
          16, 0, 0);
    }
  }

  // wt fill while DMA is in flight (independent LDS region)
  if (tid < 64) wt[tid >> 2][540 + (tid & 3)] = 0;
  for (int i = tid; i < 8640; i += 256) {
    int co_ = i / 540, r = i % 540, ci = r / 3, tap = r % 3;
    wt[co_][tap * 180 + ci] = f2bf(w1[i]);
  }
  __syncthreads();   // drains vmcnt(0) (DMA) + lgkmcnt

  const int co = lane & 15;
  const int kgrp = lane >> 4;
  const int kg = kgrp * 8;
  const int R0 = kgrp * 4;
  const int bb = wv >> 1;
  const int b = b0 + bb;
  const int t0 = (wv & 1) * 16;
  const float* pr = xsf + bb * 6120 + (t0 + co) * 180;  // 16B-aligned patch
  const float bias = b1[co];
  f32x4 acc = {bias, bias, bias, bias};

#pragma unroll
  for (int s = 0; s < 17; ++s) {               // k = s*32+kg; k>=540 weight-zero
    f32x4 lo = *(const f32x4*)(pr + s * 32 + kg);
    f32x4 hi = *(const f32x4*)(pr + s * 32 + kg + 4);
    bf16x8 a0;
    a0[0] = (short)f2bf(lo[0]); a0[1] = (short)f2bf(lo[1]);
    a0[2] = (short)f2bf(lo[2]); a0[3] = (short)f2bf(lo[3]);
    a0[4] = (short)f2bf(hi[0]); a0[5] = (short)f2bf(hi[1]);
    a0[6] = (short)f2bf(hi[2]); a0[7] = (short)f2bf(hi[3]);
    bf16x8 wf = *(const bf16x8*)&wt[co][s * 32 + kg];
    acc = mfma16(a0, wf, acc);
  }

  // epilogue: y1 [B][16][32] + BN partials
  float s_ = 0.f, q_ = 0.f;
#pragma unroll
  for (int r = 0; r < 4; ++r) { s_ += acc[r]; q_ += acc[r] * acc[r]; }
  *(float4*)(y1 + (size_t)b * 512 + co * 32 + t0 + R0) =
      make_float4(acc[0], acc[1], acc[2], acc[3]);
  s_ += __shfl_xor(s_, 16); q_ += __shfl_xor(q_, 16);
  s_ += __shfl_xor(s_, 32); q_ += __shfl_xor(q_, 32);
  if (lane < 16) { sp[wv][co] = s_; sq[wv][co] = q_; }
  __syncthreads();
  if (tid < 32) {
    int ss = tid >> 4, c = tid & 15;
    float v = ss ? (sq[0][c] + sq[1][c] + sq[2][c] + sq[3][c])
                 : (sp[0][c] + sp[1][c] + sp[2][c] + sp[3][c]);
    p1[blockIdx.x * 32 + ss * 16 + c] = v;
  }
}

// p1: [2048][32] -> per-channel scale/shift
__global__ __launch_bounds__(1024) void k_stats1(
    const float* __restrict__ p1, const float* __restrict__ g,
    const float* __restrict__ bb, float* __restrict__ sc)
{
  __shared__ float red[32][32];
  __shared__ float tot[32];
  const int tid = threadIdx.x;
  const int col = tid & 31, rg = tid >> 5;
  float a = 0;
  for (int r = rg; r < 2048; r += 32) a += p1[r * 32 + col];
  red[rg][col] = a;
  __syncthreads();
  if (tid < 32) {
    float t = 0;
    for (int i = 0; i < 32; ++i) t += red[i][tid];
    tot[tid] = t;
  }
  __syncthreads();
  if (tid < 16) {
    const float inv = 1.0f / 131072.0f;
    float m = tot[tid] * inv;
    float var = tot[16 + tid] * inv - m * m;
    float s = g[tid] * rsqrtf(fmaxf(var, 0.0f) + 1e-5f);
    sc[tid] = s;
    sc[16 + tid] = bb[tid] - m * s;
  }
}

// -------- conv2: bn1+leaky(y1) -> y2 [B,8,30] + BN2 partials --------
__global__ __launch_bounds__(256) void k_conv2(
    const float* __restrict__ y1, const float* __restrict__ sc,
    const float* __restrict__ w2, const float* __restrict__ b2,
    float* __restrict__ y2, float* __restrict__ p2)
{
  __shared__ float a1[8][16][33];
  __shared__ float w2s[384];
  __shared__ float sp[4][8][2];
  const int tid = threadIdx.x;
  const int b0 = blockIdx.x * 8;
  for (int i = tid; i < 384; i += 256) w2s[i] = w2[i];
  for (int i = tid; i < 4096; i += 256) {
    int bb = i >> 9, c = (i >> 5) & 15, t = i & 31;
    float v = y1[(size_t)(b0 + bb) * 512 + c * 32 + t] * sc[c] + sc[16 + c];
    a1[bb][c][t] = leaky(v);
  }
  __syncthreads();
  float acc[8];
  const int bb = tid / 30, t = tid % 30;
  const bool act = tid < 240;
#pragma unroll
  for (int co = 0; co < 8; ++co) acc[co] = act ? b2[co] : 0.0f;
  if (act) {
    for (int ci = 0; ci < 16; ++ci) {
      float x0 = a1[bb][ci][t], x1 = a1[bb][ci][t + 1], x2 = a1[bb][ci][t + 2];
#pragma unroll
      for (int co = 0; co < 8; ++co) {
        const float* wp = &w2s[co * 48 + ci * 3];
        acc[co] += x0 * wp[0] + x1 * wp[1] + x2 * wp[2];
      }
    }
    for (int co = 0; co < 8; ++co)
      y2[(size_t)(b0 + bb) * 240 + co * 30 + t] = acc[co];
  }
  const int w = tid >> 6;
#pragma unroll
  for (int co = 0; co < 8; ++co) {
    float s = act ? acc[co] : 0.0f;
    float q = s * s;
#pragma unroll
    for (int m = 1; m <= 32; m <<= 1) { s += __shfl_xor(s, m); q += __shfl_xor(q, m); }
    if ((tid & 63) == 0) { sp[w][co][0] = s; sp[w][co][1] = q; }
  }
  __syncthreads();
  if (tid < 16) {
    int s = tid >> 3, c = tid & 7;
    p2[blockIdx.x * 16 + s * 8 + c] = sp[0][c][s] + sp[1][c][s] + sp[2][c][s] + sp[3][c][s];
  }
}

__global__ __launch_bounds__(256) void k_stats2(
    const float* __restrict__ p2, const float* __restrict__ g,
    const float* __restrict__ bb, float* __restrict__ sc)
{
  __shared__ float red[16][16];
  __shared__ float tot[16];
  const int tid = threadIdx.x;
  const int col = tid & 15, r0 = tid >> 4;
  float a = 0;
  for (int r = r0; r < 512; r += 16) a += p2[r * 16 + col];
  red[r0][col] = a;
  __syncthreads();
  if (tid < 16) {
    float t = 0;
    for (int i = 0; i < 16; ++i) t += red[i][tid];
    tot[tid] = t;
  }
  __syncthreads();
  if (tid < 8) {
    const float inv = 1.0f / 122880.0f;
    float m = tot[tid] * inv;
    float var = tot[8 + tid] * inv - m * m;
    float s = g[tid] * rsqrtf(fmaxf(var, 0.0f) + 1e-5f);
    sc[32 + tid] = s;
    sc[40 + tid] = bb[tid] - m * s;
  }
}

// -------- conv3: bn2+leaky(y2) -> feat [28][B][8] bf16 (time-major) --------
__global__ __launch_bounds__(256) void k_conv3(
    const float* __restrict__ y2, const float* __restrict__ sc,
    const float* __restrict__ w3, const float* __restrict__ b3,
    u16* __restrict__ feat)
{
  __shared__ float a2[8][8][31];
  __shared__ float w3s[192];
  const int tid = threadIdx.x;
  const int b0 = blockIdx.x * 8;
  for (int i = tid; i < 192; i += 256) w3s[i] = w3[i];
  for (int i = tid; i < 1920; i += 256) {
    int bb = i / 240, rem = i % 240, c = rem / 30, t = rem % 30;
    float v = y2[(size_t)(b0 + bb) * 240 + c * 30 + t] * sc[32 + c] + sc[40 + c];
    a2[bb][c][t] = leaky(v);
  }
  __syncthreads();
  if (tid < 224) {
    int bb = tid / 28, t = tid % 28;
    float acc[8];
#pragma unroll
    for (int co = 0; co < 8; ++co) acc[co] = b3[co];
    for (int ci = 0; ci < 8; ++ci) {
      float x0 = a2[bb][ci][t], x1 = a2[bb][ci][t + 1], x2 = a2[bb][ci][t + 2];
#pragma unroll
      for (int co = 0; co < 8; ++co) {
        const float* wp = &w3s[co * 24 + ci * 3];
        acc[co] += x0 * wp[0] + x1 * wp[1] + x2 * wp[2];
      }
    }
    union { u16 h[8]; uint4 v; } u;
#pragma unroll
    for (int co = 0; co < 8; ++co) u.h[co] = f2bf(acc[co]);
    *(uint4*)&feat[((size_t)t * NB + b0 + bb) * 8] = u.v;
  }
}

// -------- layer-pipelined 4-layer GRU + head (log2-domain gates + setprio) --------
__global__ __launch_bounds__(1024) void k_gru_pipe(
    const u16* __restrict__ feat,
    const float* __restrict__ g0wih,   // [192][8]
    const float* __restrict__ gwih,    // [3][192][64]
    const float* __restrict__ gwhh,    // [4][192][64]
    const float* __restrict__ gbih,    // [4][192]
    const float* __restrict__ gbhh,    // [4][192]
    const float* __restrict__ ow, const float* __restrict__ ob,
    const float* __restrict__ o2w, const float* __restrict__ o2b,
    float* __restrict__ out)
{
  __shared__ __align__(16) u16 xl[2][16][40];
  __shared__ __align__(16) u16 hl[4][2][16][72];
  __shared__ float sph[4][16];
  const int tid = threadIdx.x;
  const int b0 = blockIdx.x * 16;
  const int lane = tid & 63;
  const int wv = tid >> 6;        // 0..15
  const int l = wv >> 2;          // layer 0..3
  const int c = wv & 3;           // col-group 0..3
  const int row = lane & 15;
  const int kgrp = lane >> 4;
  const int kg = kgrp * 8;
  const int R0 = kgrp * 4;
  const int cr = c * 16 + row;    // gate column 0..63

  for (int i = tid; i < 4 * 2 * 16 * 72; i += 1024) ((u16*)hl)[i] = 0;
  for (int i = tid; i < 2 * 16 * 40; i += 1024) ((u16*)xl)[i] = 0;

  // weights pre-scaled: r,z gates by L2E; n gate by 2*L2E (log2-domain gates)
  bf16x8 Wx[3][2], Wh[3][2];
  if (l == 0) {
#pragma unroll
    for (int g = 0; g < 3; ++g) {
      const float sc_ = (g == 2) ? 2.f * L2E : L2E;
      bf16x8 z;
#pragma unroll
      for (int j = 0; j < 8; ++j) z[j] = 0;
      if (kg == 0) z = ldfrag8s(g0wih + (g * 64 + cr) * 8, sc_);
      Wx[g][0] = z;
      Wx[g][1] = z;
    }
  } else {
#pragma unroll
    for (int g = 0; g < 3; ++g) {
      const float sc_ = (g == 2) ? 2.f * L2E : L2E;
#pragma unroll
      for (int s = 0; s < 2; ++s)
        Wx[g][s] = ldfrag8s(gwih + (l - 1) * 12288 + (g * 64 + cr) * 64 + s * 32 + kg, sc_);
    }
  }
#pragma unroll
  for (int g = 0; g < 3; ++g) {
    const float sc_ = (g == 2) ? 2.f * L2E : L2E;
#pragma unroll
    for (int s = 0; s < 2; ++s)
      Wh[g][s] = ldfrag8s(gwhh + l * 12288 + (g * 64 + cr) * 64 + s * 32 + kg, sc_);
  }

  const float br = (gbih[l * 192 + cr] + gbhh[l * 192 + cr]) * L2E;
  const float bz = (gbih[l * 192 + 64 + cr] + gbhh[l * 192 + 64 + cr]) * L2E;
  const float bi = gbih[l * 192 + 128 + cr] * 2.f * L2E;
  const float bh = gbhh[l * 192 + 128 + cr] * 2.f * L2E;

  float hold[4] = {0.f, 0.f, 0.f, 0.f};
  float accL[4] = {0.f, 0.f, 0.f, 0.f};
  const float owv = ow[cr];

  uint2 pf = make_uint2(0u, 0u);
  const bool xldr = (wv == 0 && lane < 32);
  if (xldr)
    pf = *(const uint2*)(feat + ((size_t)0 * NB + b0 + (lane >> 1)) * 8 + (lane & 1) * 4);
  __syncthreads();
  if (xldr)
    *(uint2*)&xl[0][lane >> 1][(lane & 1) * 4] = pf;
  __syncthreads();

  for (int tick = 0; tick < TP + 3; ++tick) {
    const int t = tick - l;
    if (t >= 0 && t < TP) {
      const int cur = t & 1, nxt = cur ^ 1;
      bf16x8 ax0, ax1, ah0, ah1;
      if (l == 0) {
        ax0 = *(const bf16x8*)&xl[cur][row][kg];
      } else {
        ax0 = *(const bf16x8*)&hl[l - 1][nxt][row][kg];      // h_{l-1}[t]
        ax1 = *(const bf16x8*)&hl[l - 1][nxt][row][32 + kg];
      }
      ah0 = *(const bf16x8*)&hl[l][cur][row][kg];            // h_l[t-1]
      ah1 = *(const bf16x8*)&hl[l][cur][row][32 + kg];
      if (xldr && t + 1 < TP)
        pf = *(const uint2*)(feat + ((size_t)(t + 1) * NB + b0 + (lane >> 1)) * 8 + (lane & 1) * 4);

      f32x4 ar = {br, br, br, br};
      f32x4 az = {bz, bz, bz, bz};
      f32x4 ai = {bi, bi, bi, bi};
      f32x4 an = {bh, bh, bh, bh};

      __builtin_amdgcn_s_setprio(1);
      ar = mfma16(ax0, Wx[0][0], ar);
      az = mfma16(ax0, Wx[1][0], az);
      ai = mfma16(ax0, Wx[2][0], ai);
      if (l != 0) {
        ar = mfma16(ax1, Wx[0][1], ar);
        az = mfma16(ax1, Wx[1][1], az);
        ai = mfma16(ax1, Wx[2][1], ai);
      }
      ar = mfma16(ah0, Wh[0][0], ar);
      ar = mfma16(ah1, Wh[0][1], ar);
      az = mfma16(ah0, Wh[1][0], az);
      az = mfma16(ah1, Wh[1][1], az);
      an = mfma16(ah0, Wh[2][0], an);
      an = mfma16(ah1, Wh[2][1], an);
      __builtin_amdgcn_s_setprio(0);

      float o2 = 0.f;
      if (l == 3) o2 = o2w[t];
      u16 hb[4];
#pragma unroll
      for (int r = 0; r < 4; ++r) {
        float rr = sigm2(ar[r]);
        float zz = sigm2(az[r]);
        float nn = tanh2(ai[r] + rr * an[r]);
        float hv = nn + zz * (hold[r] - nn);
        hold[r] = hv;
        hb[r] = f2bf(hv);
        if (l == 3) accL[r] += hv * owv * o2;
      }
#pragma unroll
      for (int r = 0; r < 4; ++r) hl[l][nxt][R0 + r][cr] = hb[r];
      if (xldr && t + 1 < TP)
        *(uint2*)&xl[(t + 1) & 1][lane >> 1][(lane & 1) * 4] = pf;
    }
    __syncthreads();
  }

  if (l == 3) {
#pragma unroll
    for (int r = 0; r < 4; ++r) {
      accL[r] += __shfl_xor(accL[r], 1);
      accL[r] += __shfl_xor(accL[r], 2);
      accL[r] += __shfl_xor(accL[r], 4);
      accL[r] += __shfl_xor(accL[r], 8);
    }
    if ((lane & 15) == 0) {
#pragma unroll
      for (int r = 0; r < 4; ++r) sph[c][R0 + r] = accL[r];
    }
  }
  __syncthreads();
  if (tid < 16) {
    float s = sph[0][tid] + sph[1][tid] + sph[2][tid] + sph[3][tid];
    float so2 = 0.f;
    for (int t = 0; t < TP; ++t) so2 += o2w[t];
    out[b0 + tid] = sigm(s + ob[0] * so2 + o2b[0]);
  }
}

extern "C" void kernel_launch(void* const* d_in, const int* in_sizes, int n_in,
                              void* d_out, int out_size, void* d_ws, size_t ws_size,
                              hipStream_t stream)
{
  const float* poses = (const float*)d_in[0];
  const float* c1w = (const float*)d_in[1];
  const float* c1b = (const float*)d_in[2];
  const float* bn1g = (const float*)d_in[3];
  const float* bn1b = (const float*)d_in[4];
  const float* c2w = (const float*)d_in[5];
  const float* c2b = (const float*)d_in[6];
  const float* bn2g = (const float*)d_in[7];
  const float* bn2b = (const float*)d_in[8];
  const float* c3w = (const float*)d_in[9];
  const float* c3b = (const float*)d_in[10];
  const float* g0wih = (const float*)d_in[11];  // [192][8]
  const float* gwih = (const float*)d_in[12];   // [3][192][64]
  const float* gwhh = (const float*)d_in[13];   // [4][192][64]
  const float* gbih = (const float*)d_in[14];   // [4][192]
  const float* gbhh = (const float*)d_in[15];   // [4][192]
  const float* ow = (const float*)d_in[16];
  const float* ob = (const float*)d_in[17];
  const float* o2w = (const float*)d_in[18];
  const float* o2b = (const float*)d_in[19];

  float* ws = (float*)d_ws;
  float* y1 = ws;                         // 2,097,152 f32
  float* y2 = ws + 2097152;               //   983,040 f32
  u16* feat = (u16*)(ws + 3080192);       //   917,504 u16
  float* p1 = ws + 3538944;               //    65,536 f32 (2048 x 32)
  float* p2 = ws + 3604480;               //     8,192 f32
  float* sc = ws + 3612672;               //        48 f32
  float* outv = (float*)d_out;

  k_conv1<<<dim3(2048), dim3(256), 0, stream>>>(poses, c1w, c1b, y1, p1);
  k_stats1<<<dim3(1), dim3(1024), 0, stream>>>(p1, bn1g, bn1b, sc);
  k_conv2<<<dim3(512), dim3(256), 0, stream>>>(y1, sc, c2w, c2b, y2, p2);
  k_stats2<<<dim3(1), dim3(256), 0, stream>>>(p2, bn2g, bn2b, sc);
  k_conv3<<<dim3(512), dim3(256), 0, stream>>>(y2, sc, c3w, c3b, feat);
  k_gru_pipe<<<dim3(256), dim3(1024), 0, stream>>>(feat, g0wih, gwih, gwhh,
                                                   gbih, gbhh, ow, ob, o2w, o2b, outv);
}

// Round 16
// 110.749 us; speedup vs baseline: 1.1406x; 1.1406x over previous
//
#include <hip/hip_runtime.h>

typedef unsigned short u16;
typedef __attribute__((ext_vector_type(8))) short bf16x8;
typedef __attribute__((ext_vector_type(4))) short bf16x4;
typedef __attribute__((ext_vector_type(4))) float f32x4;

#define TP 28
#define NB 4096
#define L2E 1.4426950408889634f

__device__ __forceinline__ u16 f2bf(float x) {
  union { float f; unsigned u; } v; v.f = x;
  unsigned u = v.u;
  return (u16)((u + 0x7fffu + ((u >> 16) & 1u)) >> 16);
}
__device__ __forceinline__ float bf2f(u16 h) {
  union { unsigned u; float f; } v; v.u = ((unsigned)h) << 16; return v.f;
}
__device__ __forceinline__ float rcp_(float x) {
  float r;
  asm("v_rcp_f32 %0, %1" : "=v"(r) : "v"(x));
  return r;
}
__device__ __forceinline__ float exp2_(float x) {
  float r;
  asm("v_exp_f32 %0, %1" : "=v"(r) : "v"(x));
  return r;
}
// log2-domain gates (weights pre-scaled by L2E / 2*L2E)
__device__ __forceinline__ float sigm2(float x) { return rcp_(1.0f + exp2_(-x)); }
__device__ __forceinline__ float tanh2(float x) { return 1.0f - 2.0f * rcp_(1.0f + exp2_(x)); }
__device__ __forceinline__ float sigm(float x) { return rcp_(1.0f + __expf(-x)); }
__device__ __forceinline__ float leaky(float x) { return x >= 0.0f ? x : 0.1f * x; }
__device__ __forceinline__ f32x4 mfma16(bf16x8 a, bf16x8 b, f32x4 c) {
  return __builtin_amdgcn_mfma_f32_16x16x32_bf16(a, b, c, 0, 0, 0);
}
__device__ __forceinline__ bf16x8 pack8s(float4 a, float4 b, float s) {
  bf16x8 f;
  f[0] = (short)f2bf(a.x * s); f[1] = (short)f2bf(a.y * s);
  f[2] = (short)f2bf(a.z * s); f[3] = (short)f2bf(a.w * s);
  f[4] = (short)f2bf(b.x * s); f[5] = (short)f2bf(b.y * s);
  f[6] = (short)f2bf(b.z * s); f[7] = (short)f2bf(b.w * s);
  return f;
}
__device__ __forceinline__ bf16x8 ldfrag8s(const float* p, float s) {
  float4 u0 = *(const float4*)p;
  float4 u1 = *(const float4*)(p + 4);
  return pack8s(u0, u1, s);
}

// ---------------- conv1: wave-independent staging + compute ----------------
// 512 thr / 8 waves / 4 batches. wt filled first (one barrier); then each wave
// stages ITS OWN 3240-float window into a private LDS region and computes with
// NO block barrier (wave-local lgkmcnt ordering). Waves pipeline independently.
__global__ __launch_bounds__(512, 4) void k_conv1(
    const float* __restrict__ poses, const float* __restrict__ w1,
    const float* __restrict__ b1, float* __restrict__ y1,
    float* __restrict__ p1)
{
  __shared__ __align__(16) u16 xw[8][3264];   // per-wave window (3240 + pad)
  __shared__ __align__(16) u16 wt[16][544];   // [co][k], k = tap*180+ci; k>=540 zero
  __shared__ float sp[8][16];
  __shared__ float sq[8][16];
  const int tid = threadIdx.x;
  const int lane = tid & 63;
  const int wv = tid >> 6;

  // wt fill (+pad zero), single early barrier
  if (tid < 64) wt[tid >> 2][540 + (tid & 3)] = 0;
  for (int i = tid; i < 8640; i += 512) {
    int co_ = i / 540, r = i % 540, ci = r / 3, tap = r % 3;
    wt[co_][tap * 180 + ci] = f2bf(w1[i]);
  }
  __syncthreads();

  // per-wave staging: batch b0+(wv>>1), t-half (wv&1); window [t0*180, t0*180+3240)
  const int b0 = blockIdx.x * 4;
  const int bb = wv >> 1;
  const int b = b0 + bb;
  const int t0 = (wv & 1) * 16;
  {
    const float4* src = (const float4*)(poses + (size_t)b * 6120 + t0 * 180);
    u16* dst = xw[wv];
    // zero wave-local tail (k = 540..543 region read by last patch)
    if (lane < 24) dst[3240 + lane] = 0;
#pragma unroll
    for (int j = 0; j < 13; ++j) {
      const int idx = j * 64 + lane;
      if (idx < 810) {
        float4 v = src[idx];
        unsigned lo = (unsigned)f2bf(v.x) | ((unsigned)f2bf(v.y) << 16);
        unsigned hi = (unsigned)f2bf(v.z) | ((unsigned)f2bf(v.w) << 16);
        *(uint2*)&dst[idx * 4] = make_uint2(lo, hi);
      }
    }
  }
  // no block barrier: this wave reads only its own region (lgkmcnt-ordered)

  const int co = lane & 15;
  const int kgrp = lane >> 4;
  const int kg = kgrp * 8;
  const int R0 = kgrp * 4;
  const u16* pr = &xw[wv][co * 180];   // lane's contiguous 540-bf16 patch
  const float bias = b1[co];
  f32x4 acc = {bias, bias, bias, bias};

#pragma unroll
  for (int s = 0; s < 17; ++s) {       // k = s*32+kg; k>=540 weight-zero
    bf16x4 lo = *(const bf16x4*)(pr + s * 32 + kg);
    bf16x4 hi = *(const bf16x4*)(pr + s * 32 + kg + 4);
    bf16x8 a0 = {lo[0], lo[1], lo[2], lo[3], hi[0], hi[1], hi[2], hi[3]};
    bf16x8 wf = *(const bf16x8*)&wt[co][s * 32 + kg];
    acc = mfma16(a0, wf, acc);
  }

  // epilogue: y1 [B][16][32] + BN partials
  float s_ = 0.f, q_ = 0.f;
#pragma unroll
  for (int r = 0; r < 4; ++r) { s_ += acc[r]; q_ += acc[r] * acc[r]; }
  *(float4*)(y1 + (size_t)b * 512 + co * 32 + t0 + R0) =
      make_float4(acc[0], acc[1], acc[2], acc[3]);
  s_ += __shfl_xor(s_, 16); q_ += __shfl_xor(q_, 16);
  s_ += __shfl_xor(s_, 32); q_ += __shfl_xor(q_, 32);
  if (lane < 16) { sp[wv][co] = s_; sq[wv][co] = q_; }
  __syncthreads();
  if (tid < 32) {
    int ss = tid >> 4, c = tid & 15;
    float v = 0.f;
#pragma unroll
    for (int w2 = 0; w2 < 8; ++w2) v += ss ? sq[w2][c] : sp[w2][c];
    p1[blockIdx.x * 32 + ss * 16 + c] = v;
  }
}

// p1: [1024][32] -> per-channel scale/shift
__global__ __launch_bounds__(1024) void k_stats1(
    const float* __restrict__ p1, const float* __restrict__ g,
    const float* __restrict__ bb, float* __restrict__ sc)
{
  __shared__ float red[32][32];
  __shared__ float tot[32];
  const int tid = threadIdx.x;
  const int col = tid & 31, rg = tid >> 5;
  float a = 0;
  for (int r = rg; r < 1024; r += 32) a += p1[r * 32 + col];
  red[rg][col] = a;
  __syncthreads();
  if (tid < 32) {
    float t = 0;
    for (int i = 0; i < 32; ++i) t += red[i][tid];
    tot[tid] = t;
  }
  __syncthreads();
  if (tid < 16) {
    const float inv = 1.0f / 131072.0f;
    float m = tot[tid] * inv;
    float var = tot[16 + tid] * inv - m * m;
    float s = g[tid] * rsqrtf(fmaxf(var, 0.0f) + 1e-5f);
    sc[tid] = s;
    sc[16 + tid] = bb[tid] - m * s;
  }
}

// -------- conv2: bn1+leaky(y1) -> y2 [B,8,30] + BN2 partials --------
__global__ __launch_bounds__(256) void k_conv2(
    const float* __restrict__ y1, const float* __restrict__ sc,
    const float* __restrict__ w2, const float* __restrict__ b2,
    float* __restrict__ y2, float* __restrict__ p2)
{
  __shared__ float a1[8][16][33];
  __shared__ float w2s[384];
  __shared__ float sp[4][8][2];
  const int tid = threadIdx.x;
  const int b0 = blockIdx.x * 8;
  for (int i = tid; i < 384; i += 256) w2s[i] = w2[i];
  for (int i = tid; i < 4096; i += 256) {
    int bb = i >> 9, c = (i >> 5) & 15, t = i & 31;
    float v = y1[(size_t)(b0 + bb) * 512 + c * 32 + t] * sc[c] + sc[16 + c];
    a1[bb][c][t] = leaky(v);
  }
  __syncthreads();
  float acc[8];
  const int bb = tid / 30, t = tid % 30;
  const bool act = tid < 240;
#pragma unroll
  for (int co = 0; co < 8; ++co) acc[co] = act ? b2[co] : 0.0f;
  if (act) {
    for (int ci = 0; ci < 16; ++ci) {
      float x0 = a1[bb][ci][t], x1 = a1[bb][ci][t + 1], x2 = a1[bb][ci][t + 2];
#pragma unroll
      for (int co = 0; co < 8; ++co) {
        const float* wp = &w2s[co * 48 + ci * 3];
        acc[co] += x0 * wp[0] + x1 * wp[1] + x2 * wp[2];
      }
    }
    for (int co = 0; co < 8; ++co)
      y2[(size_t)(b0 + bb) * 240 + co * 30 + t] = acc[co];
  }
  const int w = tid >> 6;
#pragma unroll
  for (int co = 0; co < 8; ++co) {
    float s = act ? acc[co] : 0.0f;
    float q = s * s;
#pragma unroll
    for (int m = 1; m <= 32; m <<= 1) { s += __shfl_xor(s, m); q += __shfl_xor(q, m); }
    if ((tid & 63) == 0) { sp[w][co][0] = s; sp[w][co][1] = q; }
  }
  __syncthreads();
  if (tid < 16) {
    int s = tid >> 3, c = tid & 7;
    p2[blockIdx.x * 16 + s * 8 + c] = sp[0][c][s] + sp[1][c][s] + sp[2][c][s] + sp[3][c][s];
  }
}

__global__ __launch_bounds__(256) void k_stats2(
    const float* __restrict__ p2, const float* __restrict__ g,
    const float* __restrict__ bb, float* __restrict__ sc)
{
  __shared__ float red[16][16];
  __shared__ float tot[16];
  const int tid = threadIdx.x;
  const int col = tid & 15, r0 = tid >> 4;
  float a = 0;
  for (int r = r0; r < 512; r += 16) a += p2[r * 16 + col];
  red[r0][col] = a;
  __syncthreads();
  if (tid < 16) {
    float t = 0;
    for (int i = 0; i < 16; ++i) t += red[i][tid];
    tot[tid] = t;
  }
  __syncthreads();
  if (tid < 8) {
    const float inv = 1.0f / 122880.0f;
    float m = tot[tid] * inv;
    float var = tot[8 + tid] * inv - m * m;
    float s = g[tid] * rsqrtf(fmaxf(var, 0.0f) + 1e-5f);
    sc[32 + tid] = s;
    sc[40 + tid] = bb[tid] - m * s;
  }
}

// -------- conv3: bn2+leaky(y2) -> feat [28][B][8] bf16 (time-major) --------
__global__ __launch_bounds__(256) void k_conv3(
    const float* __restrict__ y2, const float* __restrict__ sc,
    const float* __restrict__ w3, const float* __restrict__ b3,
    u16* __restrict__ feat)
{
  __shared__ float a2[8][8][31];
  __shared__ float w3s[192];
  const int tid = threadIdx.x;
  const int b0 = blockIdx.x * 8;
  for (int i = tid; i < 192; i += 256) w3s[i] = w3[i];
  for (int i = tid; i < 1920; i += 256) {
    int bb = i / 240, rem = i % 240, c = rem / 30, t = rem % 30;
    float v = y2[(size_t)(b0 + bb) * 240 + c * 30 + t] * sc[32 + c] + sc[40 + c];
    a2[bb][c][t] = leaky(v);
  }
  __syncthreads();
  if (tid < 224) {
    int bb = tid / 28, t = tid % 28;
    float acc[8];
#pragma unroll
    for (int co = 0; co < 8; ++co) acc[co] = b3[co];
    for (int ci = 0; ci < 8; ++ci) {
      float x0 = a2[bb][ci][t], x1 = a2[bb][ci][t + 1], x2 = a2[bb][ci][t + 2];
#pragma unroll
      for (int co = 0; co < 8; ++co) {
        const float* wp = &w3s[co * 24 + ci * 3];
        acc[co] += x0 * wp[0] + x1 * wp[1] + x2 * wp[2];
      }
    }
    union { u16 h[8]; uint4 v; } u;
#pragma unroll
    for (int co = 0; co < 8; ++co) u.h[co] = f2bf(acc[co]);
    *(uint4*)&feat[((size_t)t * NB + b0 + bb) * 8] = u.v;
  }
}

// -------- layer-pipelined 4-layer GRU + head (log2-domain gates + setprio) --------
__global__ __launch_bounds__(1024) void k_gru_pipe(
    const u16* __restrict__ feat,
    const float* __restrict__ g0wih,   // [192][8]
    const float* __restrict__ gwih,    // [3][192][64]
    const float* __restrict__ gwhh,    // [4][192][64]
    const float* __restrict__ gbih,    // [4][192]
    const float* __restrict__ gbhh,    // [4][192]
    const float* __restrict__ ow, const float* __restrict__ ob,
    const float* __restrict__ o2w, const float* __restrict__ o2b,
    float* __restrict__ out)
{
  __shared__ __align__(16) u16 xl[2][16][40];
  __shared__ __align__(16) u16 hl[4][2][16][72];
  __shared__ float sph[4][16];
  const int tid = threadIdx.x;
  const int b0 = blockIdx.x * 16;
  const int lane = tid & 63;
  const int wv = tid >> 6;        // 0..15
  const int l = wv >> 2;          // layer 0..3
  const int c = wv & 3;           // col-group 0..3
  const int row = lane & 15;
  const int kgrp = lane >> 4;
  const int kg = kgrp * 8;
  const int R0 = kgrp * 4;
  const int cr = c * 16 + row;    // gate column 0..63

  for (int i = tid; i < 4 * 2 * 16 * 72; i += 1024) ((u16*)hl)[i] = 0;
  for (int i = tid; i < 2 * 16 * 40; i += 1024) ((u16*)xl)[i] = 0;

  // weights pre-scaled: r,z gates by L2E; n gate by 2*L2E (log2-domain gates)
  bf16x8 Wx[3][2], Wh[3][2];
  if (l == 0) {
#pragma unroll
    for (int g = 0; g < 3; ++g) {
      const float sc_ = (g == 2) ? 2.f * L2E : L2E;
      bf16x8 z;
#pragma unroll
      for (int j = 0; j < 8; ++j) z[j] = 0;
      if (kg == 0) z = ldfrag8s(g0wih + (g * 64 + cr) * 8, sc_);
      Wx[g][0] = z;
      Wx[g][1] = z;
    }
  } else {
#pragma unroll
    for (int g = 0; g < 3; ++g) {
      const float sc_ = (g == 2) ? 2.f * L2E : L2E;
#pragma unroll
      for (int s = 0; s < 2; ++s)
        Wx[g][s] = ldfrag8s(gwih + (l - 1) * 12288 + (g * 64 + cr) * 64 + s * 32 + kg, sc_);
    }
  }
#pragma unroll
  for (int g = 0; g < 3; ++g) {
    const float sc_ = (g == 2) ? 2.f * L2E : L2E;
#pragma unroll
    for (int s = 0; s < 2; ++s)
      Wh[g][s] = ldfrag8s(gwhh + l * 12288 + (g * 64 + cr) * 64 + s * 32 + kg, sc_);
  }

  const float br = (gbih[l * 192 + cr] + gbhh[l * 192 + cr]) * L2E;
  const float bz = (gbih[l * 192 + 64 + cr] + gbhh[l * 192 + 64 + cr]) * L2E;
  const float bi = gbih[l * 192 + 128 + cr] * 2.f * L2E;
  const float bh = gbhh[l * 192 + 128 + cr] * 2.f * L2E;

  float hold[4] = {0.f, 0.f, 0.f, 0.f};
  float accL[4] = {0.f, 0.f, 0.f, 0.f};
  const float owv = ow[cr];

  uint2 pf = make_uint2(0u, 0u);
  const bool xldr = (wv == 0 && lane < 32);
  if (xldr)
    pf = *(const uint2*)(feat + ((size_t)0 * NB + b0 + (lane >> 1)) * 8 + (lane & 1) * 4);
  __syncthreads();
  if (xldr)
    *(uint2*)&xl[0][lane >> 1][(lane & 1) * 4] = pf;
  __syncthreads();

  for (int tick = 0; tick < TP + 3; ++tick) {
    const int t = tick - l;
    if (t >= 0 && t < TP) {
      const int cur = t & 1, nxt = cur ^ 1;
      bf16x8 ax0, ax1, ah0, ah1;
      if (l == 0) {
        ax0 = *(const bf16x8*)&xl[cur][row][kg];
      } else {
        ax0 = *(const bf16x8*)&hl[l - 1][nxt][row][kg];      // h_{l-1}[t]
        ax1 = *(const bf16x8*)&hl[l - 1][nxt][row][32 + kg];
      }
      ah0 = *(const bf16x8*)&hl[l][cur][row][kg];            // h_l[t-1]
      ah1 = *(const bf16x8*)&hl[l][cur][row][32 + kg];
      if (xldr && t + 1 < TP)
        pf = *(const uint2*)(feat + ((size_t)(t + 1) * NB + b0 + (lane >> 1)) * 8 + (lane & 1) * 4);

      f32x4 ar = {br, br, br, br};
      f32x4 az = {bz, bz, bz, bz};
      f32x4 ai = {bi, bi, bi, bi};
      f32x4 an = {bh, bh, bh, bh};

      __builtin_amdgcn_s_setprio(1);
      ar = mfma16(ax0, Wx[0][0], ar);
      az = mfma16(ax0, Wx[1][0], az);
      ai = mfma16(ax0, Wx[2][0], ai);
      if (l != 0) {
        ar = mfma16(ax1, Wx[0][1], ar);
        az = mfma16(ax1, Wx[1][1], az);
        ai = mfma16(ax1, Wx[2][1], ai);
      }
      ar = mfma16(ah0, Wh[0][0], ar);
      ar = mfma16(ah1, Wh[0][1], ar);
      az = mfma16(ah0, Wh[1][0], az);
      az = mfma16(ah1, Wh[1][1], az);
      an = mfma16(ah0, Wh[2][0], an);
      an = mfma16(ah1, Wh[2][1], an);
      __builtin_amdgcn_s_setprio(0);

      float o2 = 0.f;
      if (l == 3) o2 = o2w[t];
      u16 hb[4];
#pragma unroll
      for (int r = 0; r < 4; ++r) {
        float rr = sigm2(ar[r]);
        float zz = sigm2(az[r]);
        float nn = tanh2(ai[r] + rr * an[r]);
        float hv = nn + zz * (hold[r] - nn);
        hold[r] = hv;
        hb[r] = f2bf(hv);
        if (l == 3) accL[r] += hv * owv * o2;
      }
#pragma unroll
      for (int r = 0; r < 4; ++r) hl[l][nxt][R0 + r][cr] = hb[r];
      if (xldr && t + 1 < TP)
        *(uint2*)&xl[(t + 1) & 1][lane >> 1][(lane & 1) * 4] = pf;
    }
    __syncthreads();
  }

  if (l == 3) {
#pragma unroll
    for (int r = 0; r < 4; ++r) {
      accL[r] += __shfl_xor(accL[r], 1);
      accL[r] += __shfl_xor(accL[r], 2);
      accL[r] += __shfl_xor(accL[r], 4);
      accL[r] += __shfl_xor(accL[r], 8);
    }
    if ((lane & 15) == 0) {
#pragma unroll
      for (int r = 0; r < 4; ++r) sph[c][R0 + r] = accL[r];
    }
  }
  __syncthreads();
  if (tid < 16) {
    float s = sph[0][tid] + sph[1][tid] + sph[2][tid] + sph[3][tid];
    float so2 = 0.f;
    for (int t = 0; t < TP; ++t) so2 += o2w[t];
    out[b0 + tid] = sigm(s + ob[0] * so2 + o2b[0]);
  }
}

extern "C" void kernel_launch(void* const* d_in, const int* in_sizes, int n_in,
                              void* d_out, int out_size, void* d_ws, size_t ws_size,
                              hipStream_t stream)
{
  const float* poses = (const float*)d_in[0];
  const float* c1w = (const float*)d_in[1];
  const float* c1b = (const float*)d_in[2];
  const float* bn1g = (const float*)d_in[3];
  const float* bn1b = (const float*)d_in[4];
  const float* c2w = (const float*)d_in[5];
  const float* c2b = (const float*)d_in[6];
  const float* bn2g = (const float*)d_in[7];
  const float* bn2b = (const float*)d_in[8];
  const float* c3w = (const float*)d_in[9];
  const float* c3b = (const float*)d_in[10];
  const float* g0wih = (const float*)d_in[11];  // [192][8]
  const float* gwih = (const float*)d_in[12];   // [3][192][64]
  const float* gwhh = (const float*)d_in[13];   // [4][192][64]
  const float* gbih = (const float*)d_in[14];   // [4][192]
  const float* gbhh = (const float*)d_in[15];   // [4][192]
  const float* ow = (const float*)d_in[16];
  const float* ob = (const float*)d_in[17];
  const float* o2w = (const float*)d_in[18];
  const float* o2b = (const float*)d_in[19];

  float* ws = (float*)d_ws;
  float* y1 = ws;                         // 2,097,152 f32
  float* y2 = ws + 2097152;               //   983,040 f32
  u16* feat = (u16*)(ws + 3080192);       //   917,504 u16
  float* p1 = ws + 3538944;               //    32,768 f32 (1024 x 32)
  float* p2 = ws + 3604480;               //     8,192 f32
  float* sc = ws + 3612672;               //        48 f32
  float* outv = (float*)d_out;

  k_conv1<<<dim3(1024), dim3(512), 0, stream>>>(poses, c1w, c1b, y1, p1);
  k_stats1<<<dim3(1), dim3(1024), 0, stream>>>(p1, bn1g, bn1b, sc);
  k_conv2<<<dim3(512), dim3(256), 0, stream>>>(y1, sc, c2w, c2b, y2, p2);
  k_stats2<<<dim3(1), dim3(256), 0, stream>>>(p2, bn2g, bn2b, sc);
  k_conv3<<<dim3(512), dim3(256), 0, stream>>>(y2, sc, c3w, c3b, feat);
  k_gru_pipe<<<dim3(256), dim3(1024), 0, stream>>>(feat, g0wih, gwih, gwhh,
                                                   gbih, gbhh, ow, ob, o2w, o2b, outv);
}